// Round 2
// baseline (1150.930 us; speedup 1.0000x reference)
//
#include <hip/hip_runtime.h>
#include <hip/hip_bf16.h>

// Problem constants (fixed by reference)
#define V_SZ 32000
#define KCTX 3
#define D_SZ 1024
#define S_SZ 2048
#define B_SZ 2
#define M_SZ (S_SZ * B_SZ)      // 4096 rows (t*B + b)
#define KD   (KCTX * D_SZ)      // 3072
#define M1   (M_SZ + 128)       // 4224: extra 128-row tile holds pad-token rows

using bf16x8 = __attribute__((ext_vector_type(8))) __bf16;
using f32x4  = __attribute__((ext_vector_type(4))) float;

// ---------------------------------------------------------------------------
// Transpose + fp32->bf16 convert, blockwise over z:
//   per z: src_z = src + z*R*C (R x C f32 row-major) -> dst_z = dst + z*R*C
//          dst_z[c][r] = bf16(src_z[r][c])
// grid: (C/32, R/32, nblk), block: (32, 8)
// ---------------------------------------------------------------------------
__global__ void transpose_cvt(const float* __restrict__ src0,
                              __hip_bfloat16* __restrict__ dst0,
                              int R, int C) {
    const size_t zoff = (size_t)blockIdx.z * R * C;
    const float* src = src0 + zoff;
    __hip_bfloat16* dst = dst0 + zoff;
    __shared__ float tile[32][33];
    const int c0 = blockIdx.x * 32;
    const int r0 = blockIdx.y * 32;
    const int tx = threadIdx.x;   // 0..31
    const int ty = threadIdx.y;   // 0..7
#pragma unroll
    for (int j = ty; j < 32; j += 8)
        tile[j][tx] = src[(size_t)(r0 + j) * C + (c0 + tx)];
    __syncthreads();
#pragma unroll
    for (int j = ty; j < 32; j += 8)
        dst[(size_t)(c0 + j) * R + (r0 + tx)] = __float2bfloat16(tile[tx][j]);
}

// ---------------------------------------------------------------------------
// Single-token gather: A1[m][d] = bf16(emb[tok(m)][d]),  m in [0, M1)
//   m < M_SZ: tok = tokens[m]  (tokens_seq is (S,B) row-major, m = t*B+b)
//   m >= M_SZ: tok = 0 (pad rows; only row M_SZ is ever read downstream)
// grid: M1 blocks x 256 threads (1024 f32 per row = 256 float4)
// ---------------------------------------------------------------------------
__global__ void gather1(const int* __restrict__ tokens,
                        const float* __restrict__ emb,
                        __hip_bfloat16* __restrict__ A1) {
    const int m = blockIdx.x;
    const int tok = (m < M_SZ) ? tokens[m] : 0;
    const float4 v = reinterpret_cast<const float4*>(emb + (size_t)tok * D_SZ)[threadIdx.x];
    __hip_bfloat16 o[4];
    o[0] = __float2bfloat16(v.x);
    o[1] = __float2bfloat16(v.y);
    o[2] = __float2bfloat16(v.z);
    o[3] = __float2bfloat16(v.w);
    reinterpret_cast<ushort4*>(A1 + (size_t)m * D_SZ)[threadIdx.x] =
        *reinterpret_cast<ushort4*>(o);
}

// ---------------------------------------------------------------------------
// Shift-add + bias + SiLU combine:
//   H[m][d] = bf16( silu( Y[r0][d] + Y[r1][1024+d] + Y[r2][2048+d] + b1[d] ) )
//   rj = m + 2j - 6 if in range else PAD row (M_SZ), since (t-3+j)*B+b = m+2j-6
// grid: M_SZ blocks x 256 threads (float4 over d)
// ---------------------------------------------------------------------------
__global__ void combine_silu(const float* __restrict__ Y,
                             const float* __restrict__ b1,
                             __hip_bfloat16* __restrict__ H) {
    const int m = blockIdx.x;
    const int d4 = threadIdx.x;                       // float4 index 0..255
    const int r0 = (m >= 6) ? m - 6 : M_SZ;
    const int r1 = (m >= 4) ? m - 4 : M_SZ;
    const int r2 = (m >= 2) ? m - 2 : M_SZ;
    const float4* Yv = reinterpret_cast<const float4*>(Y);
    const float4 y0 = Yv[(size_t)r0 * 768 + d4];          // chunk j=0
    const float4 y1 = Yv[(size_t)r1 * 768 + 256 + d4];    // chunk j=1
    const float4 y2 = Yv[(size_t)r2 * 768 + 512 + d4];    // chunk j=2
    const float4 bb = reinterpret_cast<const float4*>(b1)[d4];
    float x[4] = {y0.x + y1.x + y2.x + bb.x, y0.y + y1.y + y2.y + bb.y,
                  y0.z + y1.z + y2.z + bb.z, y0.w + y1.w + y2.w + bb.w};
    __hip_bfloat16 o[4];
#pragma unroll
    for (int i = 0; i < 4; ++i) {
        const float s = x[i] / (1.0f + __expf(-x[i]));    // silu
        o[i] = __float2bfloat16(s);
    }
    reinterpret_cast<ushort4*>(H + (size_t)m * D_SZ)[d4] =
        *reinterpret_cast<ushort4*>(o);
}

// ---------------------------------------------------------------------------
// bf16 MFMA GEMM, m97 structure: 128x128 tile, BK=64, 4 waves (2x2 of 64x64),
// global_load_lds width-16 staging, 2-barrier K-loop.
// 1-D grid with bijective XCD-chunk swizzle + M-fastest order inside each XCD
// chunk (concurrent blocks on an XCD share the same B-panel -> L2 reuse).
// A: M x K bf16 row-major.  BT: N x K bf16 row-major (B transposed).
// EPI==1: C = f32(acc + bias[n])   EPI==2: C = f32(acc)
// ---------------------------------------------------------------------------
#define TM 128
#define TN 128
#define TK 64

template <int EPI>
__global__ __launch_bounds__(256) void gemm_bt(
    const unsigned short* __restrict__ A,
    const unsigned short* __restrict__ BT,
    const float* __restrict__ bias,
    float* __restrict__ C, int M, int N, int K) {
    __shared__ unsigned short lsA[TM * TK];
    __shared__ unsigned short lsB[TN * TK];

    const int tid  = threadIdx.x;
    const int lane = tid & 63;
    const int w    = tid >> 6;          // wave 0..3
    const int wm   = (w >> 1) * 64;     // wave row offset in tile
    const int wn   = (w & 1) * 64;      // wave col offset in tile

    // XCD-aware bijective swizzle (nwg % 8 == 0 by construction), M-fastest
    const int nwg  = gridDim.x;
    const int q    = nwg >> 3;
    const int wgid = (blockIdx.x & 7) * q + (blockIdx.x >> 3);
    const int mt   = M >> 7;            // # of 128-row tiles
    const int m_tile = wgid % mt;
    const int n_tile = wgid / mt;
    const int m0 = m_tile * TM;
    const int n0 = n_tile * TN;

    f32x4 acc[4][4] = {};

    for (int k0 = 0; k0 < K; k0 += TK) {
        __syncthreads();   // all waves done computing previous tile
        // ---- stage A and B tiles: 128 rows x 64 cols bf16 = 8 x 16B per row
#pragma unroll
        for (int i = 0; i < 4; ++i) {
            const int s = i * 256 + tid;     // segment id 0..1023
            const int r = s >> 3;            // tile row
            const int c = s & 7;             // 16B chunk in row
            const unsigned short* srcA = A + (size_t)(m0 + r) * K + k0 + c * 8;
            __builtin_amdgcn_global_load_lds(
                (const __attribute__((address_space(1))) void*)srcA,
                (__attribute__((address_space(3))) void*)(lsA + s * 8), 16, 0, 0);
            const unsigned short* srcB = BT + (size_t)(n0 + r) * K + k0 + c * 8;
            __builtin_amdgcn_global_load_lds(
                (const __attribute__((address_space(1))) void*)srcB,
                (__attribute__((address_space(3))) void*)(lsB + s * 8), 16, 0, 0);
        }
        __syncthreads();   // loads drained (vmcnt(0) before s_barrier)

        // ---- compute: 2 k-slices of 32, 4x4 16x16 fragments per wave
#pragma unroll
        for (int kk = 0; kk < 2; ++kk) {
            const int kb = kk * 32 + (lane >> 4) * 8;
            bf16x8 a[4], b[4];
#pragma unroll
            for (int mi = 0; mi < 4; ++mi)
                a[mi] = *reinterpret_cast<const bf16x8*>(
                    &lsA[(wm + mi * 16 + (lane & 15)) * TK + kb]);
#pragma unroll
            for (int ni = 0; ni < 4; ++ni)
                b[ni] = *reinterpret_cast<const bf16x8*>(
                    &lsB[(wn + ni * 16 + (lane & 15)) * TK + kb]);
#pragma unroll
            for (int mi = 0; mi < 4; ++mi)
#pragma unroll
                for (int ni = 0; ni < 4; ++ni)
                    acc[mi][ni] = __builtin_amdgcn_mfma_f32_16x16x32_bf16(
                        a[mi], b[ni], acc[mi][ni], 0, 0, 0);
        }
    }

    // ---- epilogue: C/D layout col = lane&15, row = (lane>>4)*4 + r
    const int cn    = n0 + wn + (lane & 15);
    const int rbase = m0 + wm + (lane >> 4) * 4;
#pragma unroll
    for (int mi = 0; mi < 4; ++mi) {
#pragma unroll
        for (int ni = 0; ni < 4; ++ni) {
            const int col = cn + ni * 16;
            const float bv = (EPI == 1) ? bias[col] : 0.0f;
#pragma unroll
            for (int r = 0; r < 4; ++r) {
                const int row = rbase + mi * 16 + r;
                C[(size_t)row * N + col] = acc[mi][ni][r] + bv;
            }
        }
    }
}

// ---------------------------------------------------------------------------
extern "C" void kernel_launch(void* const* d_in, const int* in_sizes, int n_in,
                              void* d_out, int out_size, void* d_ws, size_t ws_size,
                              hipStream_t stream) {
    const int*   tokens = (const int*)d_in[0];
    const float* emb    = (const float*)d_in[1];
    const float* W1     = (const float*)d_in[2];
    const float* b1     = (const float*)d_in[3];
    const float* W2     = (const float*)d_in[4];
    const float* b2     = (const float*)d_in[5];
    float* out = (float*)d_out;

    // workspace layout (bytes); W2T reuses A1/W1T/Y space (dead after combine;
    // all kernels are stream-serialized so lifetimes are program-order)
    char* ws = (char*)d_ws;
    __hip_bfloat16* A1  = (__hip_bfloat16*)(ws);                 // 4224x1024 bf16 =  8,650,752
    __hip_bfloat16* W1T = (__hip_bfloat16*)(ws + 8650752);       // 3072x1024 bf16 =  6,291,456
    float*          Y   = (float*)         (ws + 14942208);      // 4224x3072 f32  = 51,904,512
    __hip_bfloat16* H   = (__hip_bfloat16*)(ws + 66846720);      // 4096x1024 bf16 =  8,388,608
    __hip_bfloat16* W2T = (__hip_bfloat16*)(ws);                 // 32000x1024 bf16= 65,536,000 (reuse)
    // total footprint: 75,235,328 bytes

    // 1. gather per-token embeddings -> A1 (4224 x 1024 bf16; tail = token 0)
    gather1<<<M1, 256, 0, stream>>>(tokens, emb, A1);
    // 2. W1 (3x 1024x1024 blocks) -> W1T blockwise transpose, bf16
    transpose_cvt<<<dim3(32, 32, 3), dim3(32, 8), 0, stream>>>(W1, W1T, 1024, 1024);
    // 3. Y = A1 @ W1T (4224 x 3072, f32, no bias)
    gemm_bt<2><<<dim3((KD / TN) * (M1 / TM)), 256, 0, stream>>>(
        (const unsigned short*)A1, (const unsigned short*)W1T, nullptr, Y, M1, KD, D_SZ);
    // 4. H = silu(shift-add(Y) + b1)  (4096 x 1024 bf16)
    combine_silu<<<M_SZ, 256, 0, stream>>>(Y, b1, H);
    // 5. W2 (1024 x 32000) -> W2T (32000 x 1024) bf16
    transpose_cvt<<<dim3(V_SZ / 32, D_SZ / 32, 1), dim3(32, 8), 0, stream>>>(W2, W2T, D_SZ, V_SZ);
    // 6. logits = H @ W2 + b2  (4096 x 32000 f32)
    gemm_bt<1><<<dim3((V_SZ / TN) * (M_SZ / TM)), 256, 0, stream>>>(
        (const unsigned short*)H, (const unsigned short*)W2T, b2, out, M_SZ, V_SZ, D_SZ);
}